// Round 1
// baseline (907.423 us; speedup 1.0000x reference)
//
#include <hip/hip_runtime.h>
#include <stdint.h>

// ---------------------------------------------------------------------------
// HConstructor (slot-attention block) on gfx950.
// Pipeline:
//   x  = LN(inputs)                    [16384,512]  (bf16 hi)
//   e0 = LN(mu + exp(ls)*noise)        [2048,512]   (bf16 hi+lo, first half of e1)
//   k = relu(x@Wk+bk), v = relu(x@Wv+bv)            (bf16, gemm128)
//   q = relu(e0@Wq+bq)                              (bf16, gemm64)
//   dots = q@k^T * SCALE  -> fp32 scratch in d_out H-region
//   attn1: rowwise softmax(+eps,renorm), top-10, updates = sum a_j v_j
//          -> e1[:,512:1024] (bf16 hi+lo)
//   h = relu(e1@W1+b1)   SPLIT bf16 (3-term) for fp32-class accuracy
//   e = h@W2+b2          SPLIT      -> OUTPUT 0 (fp32) + bf16 hi
//   k2 = relu(e@Wk+bk)   (bf16, gemm64)
//   q2 = x@Wq+bq (no relu)           (bf16, gemm128, into H-region scratch)
//   dots2 = q2@k2^T*SCALE -> OUTPUT 2 (fp32)
//   attn2: rowwise softmax over 2048, top-10 mask -> OUTPUT 1 (H)
//
// Buffer map:
//   d_out = [e: 1,048,576 f32][H: 33,554,432][dots2: 33,554,432]
//   H-region scratch: dots fp32 (exact fit); later q2_hi bf16 (16 MB).
//   dots2-region scratch: x/k/v bf16, transposed weights, e-side buffers
//     (all dead before the dots2 GEMM overwrites the region).
//   d_ws: k2_hi only (2 MB) — must not live in a region its consumer writes.
// ---------------------------------------------------------------------------

#define NN 16384
#define NE 2048
#define TOPK 10

static const float SCALE_F = 0.04419417382415922f;  // 512^-0.5
#define EPS_F 1e-8f

using bf16x8  = __attribute__((ext_vector_type(8))) __bf16;
using floatx4 = __attribute__((ext_vector_type(4))) float;

__device__ __forceinline__ unsigned short f2bf(float f) {
  union { float f; unsigned u; } v; v.f = f;
  unsigned r = v.u + 0x7fffu + ((v.u >> 16) & 1u);
  return (unsigned short)(r >> 16);
}
__device__ __forceinline__ float bf2f(unsigned short h) {
  union { unsigned u; float f; } v; v.u = ((unsigned)h) << 16;
  return v.f;
}

// ---------------- weight transpose + bf16 (hi, optional lo) ----------------
// src: K x N fp32 (row-major, in->out). dst: N x K bf16.
__global__ void transpose_cast_kernel(const float* __restrict__ src,
                                      unsigned short* __restrict__ dhi,
                                      unsigned short* __restrict__ dlo,
                                      int K, int N) {
  __shared__ float tile[32][33];
  int n0 = blockIdx.x * 32, k0 = blockIdx.y * 32;
  int tx = threadIdx.x, ty = threadIdx.y;  // 32 x 8
  for (int r = ty; r < 32; r += 8)
    tile[r][tx] = src[(size_t)(k0 + r) * N + n0 + tx];
  __syncthreads();
  for (int r = ty; r < 32; r += 8) {
    float v = tile[tx][r];
    size_t o = (size_t)(n0 + r) * K + k0 + tx;
    unsigned short h = f2bf(v);
    dhi[o] = h;
    if (dlo) dlo[o] = f2bf(v - bf2f(h));
  }
}

// ---------------- block reduce (256 threads = 4 waves) ----------------
__device__ __forceinline__ float block_sum_256(float v, float* sm4) {
#pragma unroll
  for (int off = 32; off; off >>= 1) v += __shfl_down(v, off, 64);
  __syncthreads();
  if ((threadIdx.x & 63) == 0) sm4[threadIdx.x >> 6] = v;
  __syncthreads();
  return (sm4[0] + sm4[1]) + (sm4[2] + sm4[3]);
}

// ---------------- layernorm kernels (1 row / block, 512 cols) ----------------
__global__ __launch_bounds__(256) void ln_x_kernel(
    const float* __restrict__ in, const float* __restrict__ w,
    const float* __restrict__ b, unsigned short* __restrict__ out_hi) {
  __shared__ float sm4[4];
  int row = blockIdx.x, tid = threadIdx.x;
  const float* r = in + (size_t)row * 512;
  float x0 = r[tid], x1 = r[tid + 256];
  float mu = block_sum_256(x0 + x1, sm4) * (1.0f / 512.0f);
  float d0 = x0 - mu, d1 = x1 - mu;
  float var = block_sum_256(d0 * d0 + d1 * d1, sm4) * (1.0f / 512.0f);
  float rs = rsqrtf(var + 1e-5f);
  out_hi[(size_t)row * 512 + tid]       = f2bf(d0 * rs * w[tid] + b[tid]);
  out_hi[(size_t)row * 512 + tid + 256] = f2bf(d1 * rs * w[tid + 256] + b[tid + 256]);
}

__global__ __launch_bounds__(256) void ln_e_kernel(
    const float* __restrict__ noise, const float* __restrict__ mu_e,
    const float* __restrict__ ls_e, const float* __restrict__ w,
    const float* __restrict__ b, unsigned short* __restrict__ e1_hi,
    unsigned short* __restrict__ e1_lo) {
  __shared__ float sm4[4];
  int row = blockIdx.x, tid = threadIdx.x;
  const float* r = noise + (size_t)row * 512;
  float x0 = mu_e[tid] + expf(ls_e[tid]) * r[tid];
  float x1 = mu_e[tid + 256] + expf(ls_e[tid + 256]) * r[tid + 256];
  float mu = block_sum_256(x0 + x1, sm4) * (1.0f / 512.0f);
  float d0 = x0 - mu, d1 = x1 - mu;
  float var = block_sum_256(d0 * d0 + d1 * d1, sm4) * (1.0f / 512.0f);
  float rs = rsqrtf(var + 1e-5f);
  float y0 = d0 * rs * w[tid] + b[tid];
  float y1 = d1 * rs * w[tid + 256] + b[tid + 256];
  size_t o = (size_t)row * 1024;
  unsigned short h0 = f2bf(y0), h1 = f2bf(y1);
  e1_hi[o + tid] = h0;             e1_lo[o + tid] = f2bf(y0 - bf2f(h0));
  e1_hi[o + tid + 256] = h1;       e1_lo[o + tid + 256] = f2bf(y1 - bf2f(h1));
}

// ---------------- GEMM, 128x128 tile, single bf16 ----------------
// C[M,N] = act(alpha * A[M,K] @ B[N,K]^T + bias). M,N multiples of 128, K of 32.
template <bool RELU, bool HAS_BIAS, bool WF32, bool WBF16>
__global__ __launch_bounds__(256) void gemm128_kernel(
    const unsigned short* __restrict__ A, int lda,
    const unsigned short* __restrict__ B, int K,
    const float* __restrict__ bias, float alpha,
    float* __restrict__ Cf, int ldc,
    unsigned short* __restrict__ Cb, int ldcb) {
  __shared__ __align__(16) unsigned short As[128 * 32];
  __shared__ __align__(16) unsigned short Bs[128 * 32];
  int tid = threadIdx.x;
  int wave = tid >> 6, lane = tid & 63;
  int lrow = lane & 15, quad = lane >> 4;
  size_t bm = (size_t)blockIdx.x * 128, bn = (size_t)blockIdx.y * 128;

  int c0 = tid, c1 = tid + 256;  // 16B chunks of the 128x32 tile
  const unsigned short* pA0 = A + (bm + (c0 >> 2)) * lda + ((c0 & 3) << 3);
  const unsigned short* pA1 = A + (bm + (c1 >> 2)) * lda + ((c1 & 3) << 3);
  const unsigned short* pB0 = B + (bn + (c0 >> 2)) * (size_t)K + ((c0 & 3) << 3);
  const unsigned short* pB1 = B + (bn + (c1 >> 2)) * (size_t)K + ((c1 & 3) << 3);

  floatx4 zero4 = {0.f, 0.f, 0.f, 0.f};
  floatx4 acc[2][8];
#pragma unroll
  for (int i = 0; i < 2; ++i)
#pragma unroll
    for (int t = 0; t < 8; ++t) acc[i][t] = zero4;

  for (int k0 = 0; k0 < K; k0 += 32) {
    uint4 a0 = *(const uint4*)(pA0 + k0);
    uint4 a1 = *(const uint4*)(pA1 + k0);
    uint4 b0 = *(const uint4*)(pB0 + k0);
    uint4 b1 = *(const uint4*)(pB1 + k0);
    __syncthreads();
    *(uint4*)&As[c0 * 8] = a0;
    *(uint4*)&As[c1 * 8] = a1;
    *(uint4*)&Bs[c0 * 8] = b0;
    *(uint4*)&Bs[c1 * 8] = b1;
    __syncthreads();
    bf16x8 af0 = *(const bf16x8*)&As[(wave * 32 + lrow) * 32 + quad * 8];
    bf16x8 af1 = *(const bf16x8*)&As[(wave * 32 + 16 + lrow) * 32 + quad * 8];
#pragma unroll
    for (int t = 0; t < 8; ++t) {
      bf16x8 bfr = *(const bf16x8*)&Bs[(t * 16 + lrow) * 32 + quad * 8];
      acc[0][t] = __builtin_amdgcn_mfma_f32_16x16x32_bf16(af0, bfr, acc[0][t], 0, 0, 0);
      acc[1][t] = __builtin_amdgcn_mfma_f32_16x16x32_bf16(af1, bfr, acc[1][t], 0, 0, 0);
    }
  }
#pragma unroll
  for (int i = 0; i < 2; ++i) {
    size_t row0 = bm + wave * 32 + i * 16 + quad * 4;  // C/D: row = quad*4+reg
#pragma unroll
    for (int t = 0; t < 8; ++t) {
      int col = (int)bn + t * 16 + lrow;               // C/D: col = lane&15
      float bv = HAS_BIAS ? bias[col] : 0.0f;
#pragma unroll
      for (int r = 0; r < 4; ++r) {
        float v = acc[i][t][r] * alpha + bv;
        if (RELU) v = fmaxf(v, 0.0f);
        if (WF32) Cf[(row0 + r) * (size_t)ldc + col] = v;
        if (WBF16) Cb[(row0 + r) * (size_t)ldcb + col] = f2bf(v);
      }
    }
  }
}

// ---------------- GEMM, 64x64 tile, optional 3-term hi/lo split ----------------
template <bool SPLIT, bool RELU, bool HAS_BIAS, bool WF32, bool WHI, bool WLO>
__global__ __launch_bounds__(256) void gemm64_kernel(
    const unsigned short* __restrict__ Ahi, const unsigned short* __restrict__ Alo, int lda,
    const unsigned short* __restrict__ Bhi, const unsigned short* __restrict__ Blo, int K,
    const float* __restrict__ bias, float alpha,
    float* __restrict__ Cf, int ldc,
    unsigned short* __restrict__ Chi, unsigned short* __restrict__ Clo, int ldcb) {
  __shared__ __align__(16) unsigned short AsH[64 * 32];
  __shared__ __align__(16) unsigned short BsH[64 * 32];
  __shared__ __align__(16) unsigned short AsL[64 * 32];
  __shared__ __align__(16) unsigned short BsL[64 * 32];
  int tid = threadIdx.x, wave = tid >> 6, lane = tid & 63;
  int lrow = lane & 15, quad = lane >> 4;
  size_t bm = (size_t)blockIdx.x * 64, bn = (size_t)blockIdx.y * 64;
  int row = tid >> 2, off = (tid & 3) << 3;
  size_t aoff = (bm + row) * (size_t)lda + off;
  size_t boff = (bn + row) * (size_t)K + off;

  floatx4 zero4 = {0.f, 0.f, 0.f, 0.f};
  floatx4 acc[4];
#pragma unroll
  for (int t = 0; t < 4; ++t) acc[t] = zero4;

  for (int k0 = 0; k0 < K; k0 += 32) {
    uint4 ah = *(const uint4*)(Ahi + aoff + k0);
    uint4 bh = *(const uint4*)(Bhi + boff + k0);
    uint4 al, bl;
    if (SPLIT) {
      al = *(const uint4*)(Alo + aoff + k0);
      bl = *(const uint4*)(Blo + boff + k0);
    }
    __syncthreads();
    *(uint4*)&AsH[tid * 8] = ah;
    *(uint4*)&BsH[tid * 8] = bh;
    if (SPLIT) {
      *(uint4*)&AsL[tid * 8] = al;
      *(uint4*)&BsL[tid * 8] = bl;
    }
    __syncthreads();
    int ai = (wave * 16 + lrow) * 32 + quad * 8;
    bf16x8 aH = *(const bf16x8*)&AsH[ai];
    bf16x8 aL;
    if (SPLIT) aL = *(const bf16x8*)&AsL[ai];
#pragma unroll
    for (int t = 0; t < 4; ++t) {
      int bi = (t * 16 + lrow) * 32 + quad * 8;
      bf16x8 bH = *(const bf16x8*)&BsH[bi];
      acc[t] = __builtin_amdgcn_mfma_f32_16x16x32_bf16(aH, bH, acc[t], 0, 0, 0);
      if (SPLIT) {
        bf16x8 bL = *(const bf16x8*)&BsL[bi];
        acc[t] = __builtin_amdgcn_mfma_f32_16x16x32_bf16(aH, bL, acc[t], 0, 0, 0);
        acc[t] = __builtin_amdgcn_mfma_f32_16x16x32_bf16(aL, bH, acc[t], 0, 0, 0);
      }
    }
  }
  size_t row0 = bm + wave * 16 + quad * 4;
#pragma unroll
  for (int t = 0; t < 4; ++t) {
    int col = (int)bn + t * 16 + lrow;
    float bv = HAS_BIAS ? bias[col] : 0.0f;
#pragma unroll
    for (int r = 0; r < 4; ++r) {
      float v = acc[t][r] * alpha + bv;
      if (RELU) v = fmaxf(v, 0.0f);
      if (WF32) Cf[(row0 + r) * (size_t)ldc + col] = v;
      if (WHI) {
        unsigned short h = f2bf(v);
        Chi[(row0 + r) * (size_t)ldcb + col] = h;
        if (WLO) Clo[(row0 + r) * (size_t)ldcb + col] = f2bf(v - bf2f(h));
      }
    }
  }
}

// ---------------- top-k merge (shared by both attention kernels) ----------------
__device__ __forceinline__ bool better(float v1, int i1, float v2, int i2) {
  return (v1 > v2) || (v1 == v2 && i1 < i2);
}

// 256*TOPK candidates in smv/smi -> TOPK winners in wv/wi (extraction).
__device__ void topk_merge(float* smv, int* smi, float* rv4, int* ri4, int* rs4,
                           float* wv, int* wi) {
  int tid = threadIdx.x, wave = tid >> 6, lane = tid & 63;
  for (int rnd = 0; rnd < TOPK; ++rnd) {
    float bv = -INFINITY; int bi = 0x7fffffff; int bs = tid * TOPK;
#pragma unroll
    for (int j = 0; j < TOPK; ++j) {
      int s = tid * TOPK + j;
      float v = smv[s]; int ix = smi[s];
      if (better(v, ix, bv, bi)) { bv = v; bi = ix; bs = s; }
    }
#pragma unroll
    for (int offr = 32; offr; offr >>= 1) {
      float ov = __shfl_down(bv, offr, 64);
      int oi = __shfl_down(bi, offr, 64);
      int os = __shfl_down(bs, offr, 64);
      if (better(ov, oi, bv, bi)) { bv = ov; bi = oi; bs = os; }
    }
    if (lane == 0) { rv4[wave] = bv; ri4[wave] = bi; rs4[wave] = bs; }
    __syncthreads();
    if (tid == 0) {
      float xv = rv4[0]; int xi = ri4[0]; int xs = rs4[0];
#pragma unroll
      for (int w = 1; w < 4; ++w)
        if (better(rv4[w], ri4[w], xv, xi)) { xv = rv4[w]; xi = ri4[w]; xs = rs4[w]; }
      wv[rnd] = xv; wi[rnd] = xi; smv[xs] = -INFINITY;
    }
    __syncthreads();
  }
}

// ---------------- attention 1: softmax(+eps, renorm), top-10, updates ----------------
__global__ __launch_bounds__(256) void attn1_kernel(
    const float* __restrict__ dots,          // NE x NN
    const unsigned short* __restrict__ vhi,  // NN x 512 bf16
    unsigned short* __restrict__ e1_hi, unsigned short* __restrict__ e1_lo) {
  __shared__ float smv[256 * TOPK];
  __shared__ int smi[256 * TOPK];
  __shared__ float rv4[4]; __shared__ int ri4[4]; __shared__ int rs4[4];
  __shared__ float wv[TOPK]; __shared__ int wi[TOPK];
  __shared__ float sm4[4];
  __shared__ float wa[TOPK];

  int tid = threadIdx.x;
  int rowi = blockIdx.x;
  const float* r = dots + (size_t)rowi * NN;

  float lv[TOPK]; int li[TOPK];
#pragma unroll
  for (int j = 0; j < TOPK; ++j) { lv[j] = -INFINITY; li[j] = 0x7fffffff; }
  float m = -INFINITY;
  for (int i = 0; i < NN / 256; ++i) {
    int idx = tid + (i << 8);
    float v = r[idx];
    m = fmaxf(m, v);
    if (v > lv[TOPK - 1]) {  // scan order = ascending idx; strict > keeps earlier on ties
      float cv = v; int ci = idx;
#pragma unroll
      for (int j = 0; j < TOPK; ++j) {
        bool sw = (cv > lv[j]);
        float tv = sw ? lv[j] : cv; int ti = sw ? li[j] : ci;
        lv[j] = sw ? cv : lv[j];    li[j] = sw ? ci : li[j];
        cv = tv; ci = ti;
      }
    }
  }
#pragma unroll
  for (int offr = 32; offr; offr >>= 1) m = fmaxf(m, __shfl_down(m, offr, 64));
  __syncthreads();
  if ((tid & 63) == 0) sm4[tid >> 6] = m;
  __syncthreads();
  m = fmaxf(fmaxf(sm4[0], sm4[1]), fmaxf(sm4[2], sm4[3]));

  float s = 0.f;
  for (int i = 0; i < NN / 256; ++i) s += expf(r[tid + (i << 8)] - m);
  float Z = block_sum_256(s, sm4);

#pragma unroll
  for (int j = 0; j < TOPK; ++j) { smv[tid * TOPK + j] = lv[j]; smi[tid * TOPK + j] = li[j]; }
  __syncthreads();
  topk_merge(smv, smi, rv4, ri4, rs4, wv, wi);

  const float inv_den = 1.0f / (1.0f + (float)NN * EPS_F);  // sum(p+eps) = 1 + N*eps
  if (tid < TOPK) wa[tid] = (expf(wv[tid] - m) / Z + EPS_F) * inv_den;
  __syncthreads();

  float u0 = 0.f, u1 = 0.f;
#pragma unroll
  for (int j = 0; j < TOPK; ++j) {
    float a = wa[j];
    const unsigned short* vr = vhi + (size_t)wi[j] * 512;
    u0 += a * bf2f(vr[tid]);
    u1 += a * bf2f(vr[tid + 256]);
  }
  size_t o = (size_t)rowi * 1024 + 512;
  unsigned short h0 = f2bf(u0), h1 = f2bf(u1);
  e1_hi[o + tid] = h0;             e1_lo[o + tid] = f2bf(u0 - bf2f(h0));
  e1_hi[o + tid + 256] = h1;       e1_lo[o + tid + 256] = f2bf(u1 - bf2f(h1));
}

// ---------------- attention 2: softmax over 2048, top-10 mask -> H ----------------
__global__ __launch_bounds__(256) void attn2_kernel(const float* __restrict__ dots2,
                                                    float* __restrict__ Hout) {
  __shared__ float smv[256 * TOPK];
  __shared__ int smi[256 * TOPK];
  __shared__ float rv4[4]; __shared__ int ri4[4]; __shared__ int rs4[4];
  __shared__ float wv[TOPK]; __shared__ int wi[TOPK];
  __shared__ float sm4[4];

  int tid = threadIdx.x;
  int rowi = blockIdx.x;
  const float* r = dots2 + (size_t)rowi * NE;
  float d[NE / 256];
  float m = -INFINITY;
#pragma unroll
  for (int i = 0; i < NE / 256; ++i) {
    d[i] = r[tid + (i << 8)];
    m = fmaxf(m, d[i]);
  }
#pragma unroll
  for (int offr = 32; offr; offr >>= 1) m = fmaxf(m, __shfl_down(m, offr, 64));
  __syncthreads();
  if ((tid & 63) == 0) sm4[tid >> 6] = m;
  __syncthreads();
  m = fmaxf(fmaxf(sm4[0], sm4[1]), fmaxf(sm4[2], sm4[3]));

  float s = 0.f;
#pragma unroll
  for (int i = 0; i < NE / 256; ++i) s += expf(d[i] - m);
  float Z = block_sum_256(s, sm4);
  float invZ = 1.0f / Z;

  float lv[TOPK]; int li[TOPK];
#pragma unroll
  for (int j = 0; j < TOPK; ++j) { lv[j] = -INFINITY; li[j] = 0x7fffffff; }
#pragma unroll
  for (int i = 0; i < NE / 256; ++i) {
    int idx = tid + (i << 8);
    float cv = d[i]; int ci = idx;
    if (cv > lv[TOPK - 1]) {
#pragma unroll
      for (int j = 0; j < TOPK; ++j) {
        bool sw = (cv > lv[j]);
        float tv = sw ? lv[j] : cv; int ti = sw ? li[j] : ci;
        lv[j] = sw ? cv : lv[j];    li[j] = sw ? ci : li[j];
        cv = tv; ci = ti;
      }
    }
  }
#pragma unroll
  for (int j = 0; j < TOPK; ++j) { smv[tid * TOPK + j] = lv[j]; smi[tid * TOPK + j] = li[j]; }
  __syncthreads();
  topk_merge(smv, smi, rv4, ri4, rs4, wv, wi);

  float* hr = Hout + (size_t)rowi * NE;
#pragma unroll
  for (int i = 0; i < NE / 256; ++i) {
    int idx = tid + (i << 8);
    bool sel = false;
#pragma unroll
    for (int j = 0; j < TOPK; ++j) sel = sel || (wi[j] == idx);
    hr[idx] = sel ? expf(d[i] - m) * invZ : 0.0f;
  }
}

// ---------------------------------------------------------------------------
extern "C" void kernel_launch(void* const* d_in, const int* in_sizes, int n_in,
                              void* d_out, int out_size, void* d_ws, size_t ws_size,
                              hipStream_t stream) {
  (void)in_sizes; (void)n_in; (void)out_size; (void)ws_size;
  const float* inputs  = (const float*)d_in[0];
  const float* noise   = (const float*)d_in[1];
  const float* edges_mu = (const float*)d_in[2];
  const float* edges_ls = (const float*)d_in[3];
  const float* Wq = (const float*)d_in[4];
  const float* bq = (const float*)d_in[5];
  const float* Wk = (const float*)d_in[6];
  const float* bk = (const float*)d_in[7];
  const float* Wv = (const float*)d_in[8];
  const float* bv = (const float*)d_in[9];
  const float* W1 = (const float*)d_in[10];
  const float* b1 = (const float*)d_in[11];
  const float* W2 = (const float*)d_in[12];
  const float* b2 = (const float*)d_in[13];
  const float* ln_in_w = (const float*)d_in[14];
  const float* ln_in_b = (const float*)d_in[15];
  const float* ln_e_w = (const float*)d_in[16];
  const float* ln_e_b = (const float*)d_in[17];

  float* out_e  = (float*)d_out;                  // [2048,512]
  float* out_H  = out_e + (size_t)NE * 512;       // [16384,2048]
  float* out_d2 = out_H + (size_t)NN * NE;        // [16384,2048]

  const size_t MB = 1024 * 1024;
  // scratch inside the dots2 output region (dead before the dots2 GEMM writes it)
  unsigned char* sc = (unsigned char*)out_d2;
  unsigned short* x_hi  = (unsigned short*)(sc);                       // 16 MB
  unsigned short* k_hi  = (unsigned short*)(sc + 16 * MB);             // 16 MB
  unsigned short* v_hi  = (unsigned short*)(sc + 32 * MB);             // 16 MB
  unsigned short* WqT   = (unsigned short*)(sc + 48 * MB);             // 512 KB
  unsigned short* WkT   = (unsigned short*)(sc + 48 * MB + 512 * 1024);
  unsigned short* WvT   = (unsigned short*)(sc + 48 * MB + 1024 * 1024);
  unsigned short* W1Th  = (unsigned short*)(sc + 48 * MB + 1536 * 1024);  // 1 MB
  unsigned short* W1Tl  = (unsigned short*)(sc + 48 * MB + 2560 * 1024);  // 1 MB
  unsigned short* W2Th  = (unsigned short*)(sc + 48 * MB + 3584 * 1024);
  unsigned short* W2Tl  = (unsigned short*)(sc + 48 * MB + 4096 * 1024);
  unsigned short* e1_hi = (unsigned short*)(sc + 56 * MB);             // 4 MB [2048,1024]
  unsigned short* e1_lo = (unsigned short*)(sc + 60 * MB);             // 4 MB
  unsigned short* q_hi  = (unsigned short*)(sc + 64 * MB);             // 2 MB
  unsigned short* h_hi  = (unsigned short*)(sc + 66 * MB);             // 2 MB
  unsigned short* h_lo  = (unsigned short*)(sc + 68 * MB);             // 2 MB
  unsigned short* e_hi  = (unsigned short*)(sc + 70 * MB);             // 2 MB
  // H-region scratch: dots fp32 (exact fit), later q2_hi
  float* dots = out_H;
  unsigned short* q2_hi = (unsigned short*)out_H;  // valid after attn1 consumed dots
  // true workspace: k2_hi only (read by the GEMM that writes out_d2)
  unsigned short* k2_hi = (unsigned short*)d_ws;   // 2 MB

  dim3 tb(256);
  dim3 t32(32, 8);

  // weights: W[K,N] -> WT[N,K] bf16 (hi / hi+lo)
  transpose_cast_kernel<<<dim3(16, 16), t32, 0, stream>>>(Wq, WqT, nullptr, 512, 512);
  transpose_cast_kernel<<<dim3(16, 16), t32, 0, stream>>>(Wk, WkT, nullptr, 512, 512);
  transpose_cast_kernel<<<dim3(16, 16), t32, 0, stream>>>(Wv, WvT, nullptr, 512, 512);
  transpose_cast_kernel<<<dim3(16, 32), t32, 0, stream>>>(W1, W1Th, W1Tl, 1024, 512);
  transpose_cast_kernel<<<dim3(16, 16), t32, 0, stream>>>(W2, W2Th, W2Tl, 512, 512);

  ln_x_kernel<<<NN, tb, 0, stream>>>(inputs, ln_in_w, ln_in_b, x_hi);
  ln_e_kernel<<<NE, tb, 0, stream>>>(noise, edges_mu, edges_ls, ln_e_w, ln_e_b, e1_hi, e1_lo);

  // k = relu(x@Wk+bk), v = relu(x@Wv+bv)
  gemm128_kernel<true, true, false, true><<<dim3(128, 4), tb, 0, stream>>>(
      x_hi, 512, WkT, 512, bk, 1.f, nullptr, 0, k_hi, 512);
  gemm128_kernel<true, true, false, true><<<dim3(128, 4), tb, 0, stream>>>(
      x_hi, 512, WvT, 512, bv, 1.f, nullptr, 0, v_hi, 512);
  // q = relu(e0@Wq+bq)   (A = e1 first half, lda=1024)
  gemm64_kernel<false, true, true, false, true, false><<<dim3(32, 8), tb, 0, stream>>>(
      e1_hi, nullptr, 1024, WqT, nullptr, 512, bq, 1.f, nullptr, 0, q_hi, nullptr, 512);
  // dots = q@k^T * SCALE  -> H-region scratch
  gemm128_kernel<false, false, true, false><<<dim3(16, 128), tb, 0, stream>>>(
      q_hi, 512, k_hi, 512, nullptr, SCALE_F, dots, NN, nullptr, 0);
  // attn1 -> updates into e1[:,512:]
  attn1_kernel<<<NE, tb, 0, stream>>>(dots, v_hi, e1_hi, e1_lo);
  // h = relu(e1@W1+b1)  (SPLIT for fp32-class accuracy)
  gemm64_kernel<true, true, true, false, true, true><<<dim3(32, 8), tb, 0, stream>>>(
      e1_hi, e1_lo, 1024, W1Th, W1Tl, 1024, b1, 1.f, nullptr, 0, h_hi, h_lo, 512);
  // e = h@W2+b2  (SPLIT) -> OUTPUT 0 + bf16 hi
  gemm64_kernel<true, false, true, true, true, false><<<dim3(32, 8), tb, 0, stream>>>(
      h_hi, h_lo, 512, W2Th, W2Tl, 512, b2, 1.f, out_e, 512, e_hi, nullptr, 512);
  // k2 = relu(e@Wk+bk)
  gemm64_kernel<false, true, true, false, true, false><<<dim3(32, 8), tb, 0, stream>>>(
      e_hi, nullptr, 512, WkT, nullptr, 512, bk, 1.f, nullptr, 0, k2_hi, nullptr, 512);
  // q2 = x@Wq+bq (no relu) -> H-region scratch (dots is dead)
  gemm128_kernel<false, true, false, true><<<dim3(128, 4), tb, 0, stream>>>(
      x_hi, 512, WqT, 512, bq, 1.f, nullptr, 0, q2_hi, 512);
  // dots2 = q2@k2^T * SCALE -> OUTPUT 2 (overwrites dots2-region scratch, all dead)
  gemm128_kernel<false, false, true, false><<<dim3(128, 16), tb, 0, stream>>>(
      q2_hi, 512, k2_hi, 512, nullptr, SCALE_F, out_d2, NE, nullptr, 0);
  // attn2 -> OUTPUT 1 (H)
  attn2_kernel<<<NN, tb, 0, stream>>>(out_d2, out_H);
}

// Round 3
// 614.516 us; speedup vs baseline: 1.4766x; 1.4766x over previous
//
#include <hip/hip_runtime.h>
#include <stdint.h>

// ---------------------------------------------------------------------------
// HConstructor (slot-attention block) on gfx950.  Round 3: register top-k
// (round-2 design, compile fix: __float_as_float -> union bit cast).
//
// Pipeline:
//   x  = LN(inputs)                    [16384,512]  (bf16 hi)
//   e0 = LN(mu + exp(ls)*noise)        [2048,512]   (bf16 hi+lo, first half of e1)
//   k = relu(x@Wk+bk), v = relu(x@Wv+bv)            (bf16, gemm128)
//   q = relu(e0@Wq+bq)                              (bf16, gemm64)
//   dots = q@k^T * SCALE  -> fp32 scratch in d_out H-region
//   attn1: softmax(+eps,renorm), top-10, updates -> e1[:,512:1024] (bf16 hi+lo)
//   h = relu(e1@W1+b1)   SPLIT bf16 (3-term)
//   e = h@W2+b2          SPLIT      -> OUTPUT 0 (fp32) + bf16 hi
//   k2 = relu(e@Wk+bk); q2 = x@Wq+bq
//   dots2 = q2@k2^T*SCALE -> OUTPUT 2
//   attn2: softmax over 2048, top-10 mask -> OUTPUT 1 (H)
// ---------------------------------------------------------------------------

#define NN 16384
#define NE 2048
#define TOPK 10

static const float SCALE_F = 0.04419417382415922f;  // 512^-0.5
#define EPS_F 1e-8f

using bf16x8  = __attribute__((ext_vector_type(8))) __bf16;
using floatx4 = __attribute__((ext_vector_type(4))) float;

__device__ __forceinline__ unsigned f_as_u(float f) {
  union { float f; unsigned u; } v; v.f = f; return v.u;
}
__device__ __forceinline__ float u_as_f(unsigned u) {
  union { unsigned u; float f; } v; v.u = u; return v.f;
}

__device__ __forceinline__ unsigned short f2bf(float f) {
  unsigned u = f_as_u(f);
  unsigned r = u + 0x7fffu + ((u >> 16) & 1u);
  return (unsigned short)(r >> 16);
}
__device__ __forceinline__ float bf2f(unsigned short h) {
  return u_as_f(((unsigned)h) << 16);
}

// monotone float->u32 key (total order matches float order incl. negatives)
__device__ __forceinline__ unsigned fkey(float f) {
  unsigned u = f_as_u(f);
  return (u & 0x80000000u) ? ~u : (u | 0x80000000u);
}
__device__ __forceinline__ float funkey(unsigned k) {
  unsigned u = (k & 0x80000000u) ? (k ^ 0x80000000u) : ~k;
  return u_as_f(u);
}
// pack (value, col) so u64 max = (max value, tie -> smaller col)
__device__ __forceinline__ unsigned long long packkc(float v, int col) {
  return ((unsigned long long)fkey(v) << 32) | (unsigned)(~(unsigned)col);
}
__device__ __forceinline__ int unpack_col(unsigned long long w) {
  return (int)(~(unsigned)(w & 0xFFFFFFFFull));
}
__device__ __forceinline__ float unpack_val(unsigned long long w) {
  return funkey((unsigned)(w >> 32));
}
__device__ __forceinline__ unsigned long long shfl_xor_u64(unsigned long long x, int m) {
  unsigned lo = (unsigned)x, hi = (unsigned)(x >> 32);
  lo = __shfl_xor(lo, m, 64);
  hi = __shfl_xor(hi, m, 64);
  return ((unsigned long long)hi << 32) | lo;
}

// ---------------- weight transpose + bf16 (hi, optional lo) ----------------
__global__ void transpose_cast_kernel(const float* __restrict__ src,
                                      unsigned short* __restrict__ dhi,
                                      unsigned short* __restrict__ dlo,
                                      int K, int N) {
  __shared__ float tile[32][33];
  int n0 = blockIdx.x * 32, k0 = blockIdx.y * 32;
  int tx = threadIdx.x, ty = threadIdx.y;  // 32 x 8
  for (int r = ty; r < 32; r += 8)
    tile[r][tx] = src[(size_t)(k0 + r) * N + n0 + tx];
  __syncthreads();
  for (int r = ty; r < 32; r += 8) {
    float v = tile[tx][r];
    size_t o = (size_t)(n0 + r) * K + k0 + tx;
    unsigned short h = f2bf(v);
    dhi[o] = h;
    if (dlo) dlo[o] = f2bf(v - bf2f(h));
  }
}

// ---------------- block reduce (256 threads = 4 waves) ----------------
__device__ __forceinline__ float block_sum_256(float v, float* sm4) {
#pragma unroll
  for (int off = 32; off; off >>= 1) v += __shfl_down(v, off, 64);
  __syncthreads();
  if ((threadIdx.x & 63) == 0) sm4[threadIdx.x >> 6] = v;
  __syncthreads();
  return (sm4[0] + sm4[1]) + (sm4[2] + sm4[3]);
}

// ---------------- layernorm kernels ----------------
__global__ __launch_bounds__(256) void ln_x_kernel(
    const float* __restrict__ in, const float* __restrict__ w,
    const float* __restrict__ b, unsigned short* __restrict__ out_hi) {
  __shared__ float sm4[4];
  int row = blockIdx.x, tid = threadIdx.x;
  const float* r = in + (size_t)row * 512;
  float x0 = r[tid], x1 = r[tid + 256];
  float mu = block_sum_256(x0 + x1, sm4) * (1.0f / 512.0f);
  float d0 = x0 - mu, d1 = x1 - mu;
  float var = block_sum_256(d0 * d0 + d1 * d1, sm4) * (1.0f / 512.0f);
  float rs = rsqrtf(var + 1e-5f);
  out_hi[(size_t)row * 512 + tid]       = f2bf(d0 * rs * w[tid] + b[tid]);
  out_hi[(size_t)row * 512 + tid + 256] = f2bf(d1 * rs * w[tid + 256] + b[tid + 256]);
}

__global__ __launch_bounds__(256) void ln_e_kernel(
    const float* __restrict__ noise, const float* __restrict__ mu_e,
    const float* __restrict__ ls_e, const float* __restrict__ w,
    const float* __restrict__ b, unsigned short* __restrict__ e1_hi,
    unsigned short* __restrict__ e1_lo) {
  __shared__ float sm4[4];
  int row = blockIdx.x, tid = threadIdx.x;
  const float* r = noise + (size_t)row * 512;
  float x0 = mu_e[tid] + expf(ls_e[tid]) * r[tid];
  float x1 = mu_e[tid + 256] + expf(ls_e[tid + 256]) * r[tid + 256];
  float mu = block_sum_256(x0 + x1, sm4) * (1.0f / 512.0f);
  float d0 = x0 - mu, d1 = x1 - mu;
  float var = block_sum_256(d0 * d0 + d1 * d1, sm4) * (1.0f / 512.0f);
  float rs = rsqrtf(var + 1e-5f);
  float y0 = d0 * rs * w[tid] + b[tid];
  float y1 = d1 * rs * w[tid + 256] + b[tid + 256];
  size_t o = (size_t)row * 1024;
  unsigned short h0 = f2bf(y0), h1 = f2bf(y1);
  e1_hi[o + tid] = h0;             e1_lo[o + tid] = f2bf(y0 - bf2f(h0));
  e1_hi[o + tid + 256] = h1;       e1_lo[o + tid + 256] = f2bf(y1 - bf2f(h1));
}

// ---------------- GEMM, 128x128 tile, single bf16 ----------------
template <bool RELU, bool HAS_BIAS, bool WF32, bool WBF16>
__global__ __launch_bounds__(256) void gemm128_kernel(
    const unsigned short* __restrict__ A, int lda,
    const unsigned short* __restrict__ B, int K,
    const float* __restrict__ bias, float alpha,
    float* __restrict__ Cf, int ldc,
    unsigned short* __restrict__ Cb, int ldcb) {
  __shared__ __align__(16) unsigned short As[128 * 32];
  __shared__ __align__(16) unsigned short Bs[128 * 32];
  int tid = threadIdx.x;
  int wave = tid >> 6, lane = tid & 63;
  int lrow = lane & 15, quad = lane >> 4;
  size_t bm = (size_t)blockIdx.x * 128, bn = (size_t)blockIdx.y * 128;

  int c0 = tid, c1 = tid + 256;
  const unsigned short* pA0 = A + (bm + (c0 >> 2)) * lda + ((c0 & 3) << 3);
  const unsigned short* pA1 = A + (bm + (c1 >> 2)) * lda + ((c1 & 3) << 3);
  const unsigned short* pB0 = B + (bn + (c0 >> 2)) * (size_t)K + ((c0 & 3) << 3);
  const unsigned short* pB1 = B + (bn + (c1 >> 2)) * (size_t)K + ((c1 & 3) << 3);

  floatx4 zero4 = {0.f, 0.f, 0.f, 0.f};
  floatx4 acc[2][8];
#pragma unroll
  for (int i = 0; i < 2; ++i)
#pragma unroll
    for (int t = 0; t < 8; ++t) acc[i][t] = zero4;

  for (int k0 = 0; k0 < K; k0 += 32) {
    uint4 a0 = *(const uint4*)(pA0 + k0);
    uint4 a1 = *(const uint4*)(pA1 + k0);
    uint4 b0 = *(const uint4*)(pB0 + k0);
    uint4 b1 = *(const uint4*)(pB1 + k0);
    __syncthreads();
    *(uint4*)&As[c0 * 8] = a0;
    *(uint4*)&As[c1 * 8] = a1;
    *(uint4*)&Bs[c0 * 8] = b0;
    *(uint4*)&Bs[c1 * 8] = b1;
    __syncthreads();
    bf16x8 af0 = *(const bf16x8*)&As[(wave * 32 + lrow) * 32 + quad * 8];
    bf16x8 af1 = *(const bf16x8*)&As[(wave * 32 + 16 + lrow) * 32 + quad * 8];
#pragma unroll
    for (int t = 0; t < 8; ++t) {
      bf16x8 bfr = *(const bf16x8*)&Bs[(t * 16 + lrow) * 32 + quad * 8];
      acc[0][t] = __builtin_amdgcn_mfma_f32_16x16x32_bf16(af0, bfr, acc[0][t], 0, 0, 0);
      acc[1][t] = __builtin_amdgcn_mfma_f32_16x16x32_bf16(af1, bfr, acc[1][t], 0, 0, 0);
    }
  }
#pragma unroll
  for (int i = 0; i < 2; ++i) {
    size_t row0 = bm + wave * 32 + i * 16 + quad * 4;
#pragma unroll
    for (int t = 0; t < 8; ++t) {
      int col = (int)bn + t * 16 + lrow;
      float bv = HAS_BIAS ? bias[col] : 0.0f;
#pragma unroll
      for (int r = 0; r < 4; ++r) {
        float v = acc[i][t][r] * alpha + bv;
        if (RELU) v = fmaxf(v, 0.0f);
        if (WF32) Cf[(row0 + r) * (size_t)ldc + col] = v;
        if (WBF16) Cb[(row0 + r) * (size_t)ldcb + col] = f2bf(v);
      }
    }
  }
}

// ---------------- GEMM, 64x64 tile, optional 3-term hi/lo split ----------------
template <bool SPLIT, bool RELU, bool HAS_BIAS, bool WF32, bool WHI, bool WLO>
__global__ __launch_bounds__(256) void gemm64_kernel(
    const unsigned short* __restrict__ Ahi, const unsigned short* __restrict__ Alo, int lda,
    const unsigned short* __restrict__ Bhi, const unsigned short* __restrict__ Blo, int K,
    const float* __restrict__ bias, float alpha,
    float* __restrict__ Cf, int ldc,
    unsigned short* __restrict__ Chi, unsigned short* __restrict__ Clo, int ldcb) {
  __shared__ __align__(16) unsigned short AsH[64 * 32];
  __shared__ __align__(16) unsigned short BsH[64 * 32];
  __shared__ __align__(16) unsigned short AsL[64 * 32];
  __shared__ __align__(16) unsigned short BsL[64 * 32];
  int tid = threadIdx.x, wave = tid >> 6, lane = tid & 63;
  int lrow = lane & 15, quad = lane >> 4;
  size_t bm = (size_t)blockIdx.x * 64, bn = (size_t)blockIdx.y * 64;
  int row = tid >> 2, off = (tid & 3) << 3;
  size_t aoff = (bm + row) * (size_t)lda + off;
  size_t boff = (bn + row) * (size_t)K + off;

  floatx4 zero4 = {0.f, 0.f, 0.f, 0.f};
  floatx4 acc[4];
#pragma unroll
  for (int t = 0; t < 4; ++t) acc[t] = zero4;

  for (int k0 = 0; k0 < K; k0 += 32) {
    uint4 ah = *(const uint4*)(Ahi + aoff + k0);
    uint4 bh = *(const uint4*)(Bhi + boff + k0);
    uint4 al, bl;
    if (SPLIT) {
      al = *(const uint4*)(Alo + aoff + k0);
      bl = *(const uint4*)(Blo + boff + k0);
    }
    __syncthreads();
    *(uint4*)&AsH[tid * 8] = ah;
    *(uint4*)&BsH[tid * 8] = bh;
    if (SPLIT) {
      *(uint4*)&AsL[tid * 8] = al;
      *(uint4*)&BsL[tid * 8] = bl;
    }
    __syncthreads();
    int ai = (wave * 16 + lrow) * 32 + quad * 8;
    bf16x8 aH = *(const bf16x8*)&AsH[ai];
    bf16x8 aL;
    if (SPLIT) aL = *(const bf16x8*)&AsL[ai];
#pragma unroll
    for (int t = 0; t < 4; ++t) {
      int bi = (t * 16 + lrow) * 32 + quad * 8;
      bf16x8 bH = *(const bf16x8*)&BsH[bi];
      acc[t] = __builtin_amdgcn_mfma_f32_16x16x32_bf16(aH, bH, acc[t], 0, 0, 0);
      if (SPLIT) {
        bf16x8 bL = *(const bf16x8*)&BsL[bi];
        acc[t] = __builtin_amdgcn_mfma_f32_16x16x32_bf16(aH, bL, acc[t], 0, 0, 0);
        acc[t] = __builtin_amdgcn_mfma_f32_16x16x32_bf16(aL, bH, acc[t], 0, 0, 0);
      }
    }
  }
  size_t row0 = bm + wave * 16 + quad * 4;
#pragma unroll
  for (int t = 0; t < 4; ++t) {
    int col = (int)bn + t * 16 + lrow;
    float bv = HAS_BIAS ? bias[col] : 0.0f;
#pragma unroll
    for (int r = 0; r < 4; ++r) {
      float v = acc[t][r] * alpha + bv;
      if (RELU) v = fmaxf(v, 0.0f);
      if (WF32) Cf[(row0 + r) * (size_t)ldc + col] = v;
      if (WHI) {
        unsigned short h = f2bf(v);
        Chi[(row0 + r) * (size_t)ldcb + col] = h;
        if (WLO) Clo[(row0 + r) * (size_t)ldcb + col] = f2bf(v - bf2f(h));
      }
    }
  }
}

// ---------------- top-4 register insertion (sorted desc; strict > keeps
// earlier-scanned equal value ahead, matching lax.top_k first-occurrence) ----
#define INSERT4(lv, li, v, col)                                   \
  do {                                                            \
    if ((v) > lv[3]) {                                            \
      float cv_ = (v); int ci_ = (col);                           \
      _Pragma("unroll")                                           \
      for (int j_ = 0; j_ < 4; ++j_) {                            \
        bool sw_ = (cv_ > lv[j_]);                                \
        float tv_ = sw_ ? lv[j_] : cv_;                           \
        int ti_ = sw_ ? li[j_] : ci_;                              \
        lv[j_] = sw_ ? cv_ : lv[j_];                              \
        li[j_] = sw_ ? ci_ : li[j_];                              \
        cv_ = tv_; ci_ = ti_;                                     \
      }                                                           \
    }                                                             \
  } while (0)

// ---------------- attention 1: 1 block (4 waves) per row of 16384 ----------
// softmax(+eps, renorm), exact top-10, updates = sum a_j v_j
__global__ __launch_bounds__(256) void attn1_kernel(
    const float* __restrict__ dots,          // NE x NN
    const unsigned short* __restrict__ vhi,  // NN x 512 bf16
    unsigned short* __restrict__ e1_hi, unsigned short* __restrict__ e1_lo) {
  __shared__ float sm_m[4], sm_s[4];
  __shared__ unsigned long long wbest[4];
  __shared__ unsigned long long wkey_s[TOPK];

  int tid = threadIdx.x, wave = tid >> 6, lane = tid & 63;
  int rowi = blockIdx.x;
  const float4* r4 = (const float4*)(dots + (size_t)rowi * NN);

  float lv[4]; int li[4];
#pragma unroll
  for (int j = 0; j < 4; ++j) { lv[j] = -INFINITY; li[j] = 0x7fffffff; }
  unsigned long long selmask = 0ull;
  int taken = 0;

  // one streaming pass: online softmax + top-4 insertion (64 vals/thread)
  float m_loc = -INFINITY, s_loc = 0.0f;
  for (int i = 0; i < 16; ++i) {
    float4 q = r4[tid + (i << 8)];
#pragma unroll
    for (int c = 0; c < 4; ++c) {
      float v = (&q.x)[c];
      int col = ((tid + (i << 8)) << 2) + c;
      if (v > m_loc) {
        s_loc = s_loc * __expf(m_loc - v) + 1.0f;  // expf(-inf)=0 on first elem
        m_loc = v;
      } else {
        s_loc += __expf(v - m_loc);
      }
      INSERT4(lv, li, v, col);
    }
  }
  // combine (m,s) across 64 lanes (butterfly), then across 4 waves (LDS)
#pragma unroll
  for (int sft = 32; sft; sft >>= 1) {
    float om = __shfl_xor(m_loc, sft, 64);
    float os = __shfl_xor(s_loc, sft, 64);
    float M = fmaxf(m_loc, om);
    s_loc = s_loc * __expf(m_loc - M) + os * __expf(om - M);
    m_loc = M;
  }
  if (lane == 0) { sm_m[wave] = m_loc; sm_s[wave] = s_loc; }
  __syncthreads();
  float M = fmaxf(fmaxf(sm_m[0], sm_m[1]), fmaxf(sm_m[2], sm_m[3]));
  float Z = sm_s[0] * __expf(sm_m[0] - M) + sm_s[1] * __expf(sm_m[1] - M) +
            sm_s[2] * __expf(sm_m[2] - M) + sm_s[3] * __expf(sm_m[3] - M);

  // 10 extraction rounds (exact; rescan fallback if a thread wins >4 times)
  for (int rnd = 0; rnd < TOPK; ++rnd) {
    unsigned long long key;
    if (taken < 4) {
      key = packkc(lv[0], li[0]);
    } else {  // rare: re-scan this thread's 64 values from L2, excluding taken
      key = 0ull;
      for (int i = 0; i < 16; ++i) {
        float4 q = r4[tid + (i << 8)];
#pragma unroll
        for (int c = 0; c < 4; ++c) {
          int sl = i * 4 + c;
          if (!((selmask >> sl) & 1ull)) {
            int col = ((tid + (i << 8)) << 2) + c;
            unsigned long long kk = packkc((&q.x)[c], col);
            if (kk > key) key = kk;
          }
        }
      }
    }
#pragma unroll
    for (int sft = 32; sft; sft >>= 1) {
      unsigned long long ok = shfl_xor_u64(key, sft);
      if (ok > key) key = ok;
    }
    if (lane == 0) wbest[wave] = key;
    __syncthreads();
    unsigned long long w = wbest[0];
    if (wbest[1] > w) w = wbest[1];
    if (wbest[2] > w) w = wbest[2];
    if (wbest[3] > w) w = wbest[3];
    if (tid == 0) wkey_s[rnd] = w;
    int wcol = unpack_col(w);
    if (((wcol >> 2) & 255) == tid) {
      int sl = ((wcol >> 10) << 2) | (wcol & 3);
      selmask |= (1ull << sl);
      if (taken < 4) {
#pragma unroll
        for (int j = 0; j < 3; ++j) { lv[j] = lv[j + 1]; li[j] = li[j + 1]; }
      }
      ++taken;
    }
    __syncthreads();  // wbest reuse next round; also publishes wkey_s
  }

  // weighted gather of v rows
  const float inv_den = 1.0f / (1.0f + (float)NN * EPS_F);
  float invZ = 1.0f / Z;
  float u0 = 0.f, u1 = 0.f;
#pragma unroll
  for (int j = 0; j < TOPK; ++j) {
    unsigned long long w = wkey_s[j];
    int col = unpack_col(w);
    float val = unpack_val(w);
    float a = (__expf(val - M) * invZ + EPS_F) * inv_den;
    const unsigned short* vr = vhi + (size_t)col * 512;
    u0 += a * bf2f(vr[tid]);
    u1 += a * bf2f(vr[tid + 256]);
  }
  size_t o = (size_t)rowi * 1024 + 512;
  unsigned short h0 = f2bf(u0), h1 = f2bf(u1);
  e1_hi[o + tid] = h0;             e1_lo[o + tid] = f2bf(u0 - bf2f(h0));
  e1_hi[o + tid + 256] = h1;       e1_lo[o + tid + 256] = f2bf(u1 - bf2f(h1));
}

// ---------------- attention 2: 1 wave per row of 2048 (4 rows/block) -------
// softmax, exact top-10 mask -> H. No LDS, no barriers.
__global__ __launch_bounds__(256) void attn2_kernel(const float* __restrict__ dots2,
                                                    float* __restrict__ Hout) {
  int tid = threadIdx.x, wave = tid >> 6, lane = tid & 63;
  int rowi = blockIdx.x * 4 + wave;
  const float4* r4 = (const float4*)(dots2 + (size_t)rowi * NE);

  float d[32];
  float m = -INFINITY;
#pragma unroll
  for (int i = 0; i < 8; ++i) {
    float4 q = r4[lane + (i << 6)];
#pragma unroll
    for (int c = 0; c < 4; ++c) {
      d[i * 4 + c] = (&q.x)[c];
      m = fmaxf(m, d[i * 4 + c]);
    }
  }
#pragma unroll
  for (int sft = 32; sft; sft >>= 1) m = fmaxf(m, __shfl_xor(m, sft, 64));

  float s = 0.f;
#pragma unroll
  for (int j = 0; j < 32; ++j) { d[j] = __expf(d[j] - m); s += d[j]; }
#pragma unroll
  for (int sft = 32; sft; sft >>= 1) s += __shfl_xor(s, sft, 64);
  float invZ = 1.0f / s;

  // per-lane top-4 of exp-values (monotone in dots2 -> same selection)
  float lv[4]; int li[4];
#pragma unroll
  for (int j = 0; j < 4; ++j) { lv[j] = -INFINITY; li[j] = 0x7fffffff; }
#pragma unroll
  for (int i = 0; i < 8; ++i) {
#pragma unroll
    for (int c = 0; c < 4; ++c) {
      int col = ((lane + (i << 6)) << 2) + c;
      INSERT4(lv, li, d[i * 4 + c], col);
    }
  }

  unsigned selmask = 0;
  int taken = 0;
  for (int rnd = 0; rnd < TOPK; ++rnd) {
    unsigned long long key;
    if (taken < 4) {
      key = packkc(lv[0], li[0]);
    } else {  // rare exact fallback: rescan registers excluding selected
      key = 0ull;
#pragma unroll
      for (int j = 0; j < 32; ++j) {
        if (!((selmask >> j) & 1u)) {
          int col = ((lane + ((j >> 2) << 6)) << 2) + (j & 3);
          unsigned long long kk = packkc(d[j], col);
          if (kk > key) key = kk;
        }
      }
    }
#pragma unroll
    for (int sft = 32; sft; sft >>= 1) {
      unsigned long long ok = shfl_xor_u64(key, sft);
      if (ok > key) key = ok;
    }
    int wcol = unpack_col(key);
    if (((wcol >> 2) & 63) == lane) {
      int sl = ((wcol >> 8) << 2) | (wcol & 3);
      selmask |= (1u << sl);
      if (taken < 4) {
#pragma unroll
        for (int j = 0; j < 3; ++j) { lv[j] = lv[j + 1]; li[j] = li[j + 1]; }
      }
      ++taken;
    }
  }

  float* hr = Hout + (size_t)rowi * NE;
#pragma unroll
  for (int i = 0; i < 8; ++i) {
    float4 o;
#pragma unroll
    for (int c = 0; c < 4; ++c) {
      int sl = i * 4 + c;
      (&o.x)[c] = ((selmask >> sl) & 1u) ? d[sl] * invZ : 0.0f;
    }
    ((float4*)hr)[lane + (i << 6)] = o;
  }
}

// ---------------------------------------------------------------------------
extern "C" void kernel_launch(void* const* d_in, const int* in_sizes, int n_in,
                              void* d_out, int out_size, void* d_ws, size_t ws_size,
                              hipStream_t stream) {
  (void)in_sizes; (void)n_in; (void)out_size; (void)ws_size;
  const float* inputs  = (const float*)d_in[0];
  const float* noise   = (const float*)d_in[1];
  const float* edges_mu = (const float*)d_in[2];
  const float* edges_ls = (const float*)d_in[3];
  const float* Wq = (const float*)d_in[4];
  const float* bq = (const float*)d_in[5];
  const float* Wk = (const float*)d_in[6];
  const float* bk = (const float*)d_in[7];
  const float* Wv = (const float*)d_in[8];
  const float* bv = (const float*)d_in[9];
  const float* W1 = (const float*)d_in[10];
  const float* b1 = (const float*)d_in[11];
  const float* W2 = (const float*)d_in[12];
  const float* b2 = (const float*)d_in[13];
  const float* ln_in_w = (const float*)d_in[14];
  const float* ln_in_b = (const float*)d_in[15];
  const float* ln_e_w = (const float*)d_in[16];
  const float* ln_e_b = (const float*)d_in[17];

  float* out_e  = (float*)d_out;                  // [2048,512]
  float* out_H  = out_e + (size_t)NE * 512;       // [16384,2048]
  float* out_d2 = out_H + (size_t)NN * NE;        // [16384,2048]

  const size_t MB = 1024 * 1024;
  unsigned char* sc = (unsigned char*)out_d2;     // dots2-region scratch
  unsigned short* x_hi  = (unsigned short*)(sc);
  unsigned short* k_hi  = (unsigned short*)(sc + 16 * MB);
  unsigned short* v_hi  = (unsigned short*)(sc + 32 * MB);
  unsigned short* WqT   = (unsigned short*)(sc + 48 * MB);
  unsigned short* WkT   = (unsigned short*)(sc + 48 * MB + 512 * 1024);
  unsigned short* WvT   = (unsigned short*)(sc + 48 * MB + 1024 * 1024);
  unsigned short* W1Th  = (unsigned short*)(sc + 48 * MB + 1536 * 1024);
  unsigned short* W1Tl  = (unsigned short*)(sc + 48 * MB + 2560 * 1024);
  unsigned short* W2Th  = (unsigned short*)(sc + 48 * MB + 3584 * 1024);
  unsigned short* W2Tl  = (unsigned short*)(sc + 48 * MB + 4096 * 1024);
  unsigned short* e1_hi = (unsigned short*)(sc + 56 * MB);
  unsigned short* e1_lo = (unsigned short*)(sc + 60 * MB);
  unsigned short* q_hi  = (unsigned short*)(sc + 64 * MB);
  unsigned short* h_hi  = (unsigned short*)(sc + 66 * MB);
  unsigned short* h_lo  = (unsigned short*)(sc + 68 * MB);
  unsigned short* e_hi  = (unsigned short*)(sc + 70 * MB);
  float* dots = out_H;                             // H-region scratch
  unsigned short* q2_hi = (unsigned short*)out_H;  // after attn1 consumed dots
  unsigned short* k2_hi = (unsigned short*)d_ws;   // true workspace (2 MB)

  dim3 tb(256);
  dim3 t32(32, 8);

  transpose_cast_kernel<<<dim3(16, 16), t32, 0, stream>>>(Wq, WqT, nullptr, 512, 512);
  transpose_cast_kernel<<<dim3(16, 16), t32, 0, stream>>>(Wk, WkT, nullptr, 512, 512);
  transpose_cast_kernel<<<dim3(16, 16), t32, 0, stream>>>(Wv, WvT, nullptr, 512, 512);
  transpose_cast_kernel<<<dim3(16, 32), t32, 0, stream>>>(W1, W1Th, W1Tl, 1024, 512);
  transpose_cast_kernel<<<dim3(16, 16), t32, 0, stream>>>(W2, W2Th, W2Tl, 512, 512);

  ln_x_kernel<<<NN, tb, 0, stream>>>(inputs, ln_in_w, ln_in_b, x_hi);
  ln_e_kernel<<<NE, tb, 0, stream>>>(noise, edges_mu, edges_ls, ln_e_w, ln_e_b, e1_hi, e1_lo);

  gemm128_kernel<true, true, false, true><<<dim3(128, 4), tb, 0, stream>>>(
      x_hi, 512, WkT, 512, bk, 1.f, nullptr, 0, k_hi, 512);
  gemm128_kernel<true, true, false, true><<<dim3(128, 4), tb, 0, stream>>>(
      x_hi, 512, WvT, 512, bv, 1.f, nullptr, 0, v_hi, 512);
  gemm64_kernel<false, true, true, false, true, false><<<dim3(32, 8), tb, 0, stream>>>(
      e1_hi, nullptr, 1024, WqT, nullptr, 512, bq, 1.f, nullptr, 0, q_hi, nullptr, 512);
  gemm128_kernel<false, false, true, false><<<dim3(16, 128), tb, 0, stream>>>(
      q_hi, 512, k_hi, 512, nullptr, SCALE_F, dots, NN, nullptr, 0);
  attn1_kernel<<<NE, tb, 0, stream>>>(dots, v_hi, e1_hi, e1_lo);
  gemm64_kernel<true, true, true, false, true, true><<<dim3(32, 8), tb, 0, stream>>>(
      e1_hi, e1_lo, 1024, W1Th, W1Tl, 1024, b1, 1.f, nullptr, 0, h_hi, h_lo, 512);
  gemm64_kernel<true, false, true, true, true, false><<<dim3(32, 8), tb, 0, stream>>>(
      h_hi, h_lo, 512, W2Th, W2Tl, 512, b2, 1.f, out_e, 512, e_hi, nullptr, 512);
  gemm64_kernel<false, true, true, false, true, false><<<dim3(32, 8), tb, 0, stream>>>(
      e_hi, nullptr, 512, WkT, nullptr, 512, bk, 1.f, nullptr, 0, k2_hi, nullptr, 512);
  gemm128_kernel<false, true, false, true><<<dim3(128, 4), tb, 0, stream>>>(
      x_hi, 512, WqT, 512, bq, 1.f, nullptr, 0, q2_hi, 512);
  gemm128_kernel<false, false, true, false><<<dim3(128, 16), tb, 0, stream>>>(
      q2_hi, 512, k2_hi, 512, nullptr, SCALE_F, out_d2, NE, nullptr, 0);
  attn2_kernel<<<NN / 4, tb, 0, stream>>>(out_d2, out_H);
}

// Round 4
// 572.791 us; speedup vs baseline: 1.5842x; 1.0728x over previous
//
#include <hip/hip_runtime.h>
#include <stdint.h>

// ---------------------------------------------------------------------------
// HConstructor (slot-attention block) on gfx950.  Round 4:
//   - gemm128 upgraded to m97-style global_load_lds (width 16) staging
//   - k/v/q2 fused into one GEMM vs Wcat=[Wk;Wv;Wq]^T
//   - scratch remap: bf16 scratch -> H region; dots fp32 -> dots2 region
//
// Pipeline:
//   x  = LN(inputs)                    [16384,512]  (bf16)
//   e0 = LN(mu + exp(ls)*noise)        [2048,512]   (bf16 hi+lo)
//   {k,v} = relu(x@W{k,v}+b), q2 = x@Wq+bq   (one fused gemm128, N=1536)
//   q = relu(e0@Wq+bq)                              (gemm64)
//   dots = q@k^T * SCALE  -> fp32 scratch in dots2 region
//   attn1: softmax(+eps,renorm), top-10, updates -> e1[:,512:1024]
//   h = relu(e1@W1+b1)   SPLIT bf16 (3-term);  e = h@W2+b2 SPLIT -> OUTPUT 0
//   k2 = relu(e@Wk+bk)
//   dots2 = q2@k2^T*SCALE -> OUTPUT 2;  attn2 -> OUTPUT 1 (H)
// ---------------------------------------------------------------------------

#define NN 16384
#define NE 2048
#define TOPK 10

static const float SCALE_F = 0.04419417382415922f;  // 512^-0.5
#define EPS_F 1e-8f

using bf16x8  = __attribute__((ext_vector_type(8))) __bf16;
using floatx4 = __attribute__((ext_vector_type(4))) float;

__device__ __forceinline__ unsigned f_as_u(float f) {
  union { float f; unsigned u; } v; v.f = f; return v.u;
}
__device__ __forceinline__ float u_as_f(unsigned u) {
  union { unsigned u; float f; } v; v.u = u; return v.f;
}
__device__ __forceinline__ unsigned short f2bf(float f) {
  unsigned u = f_as_u(f);
  unsigned r = u + 0x7fffu + ((u >> 16) & 1u);
  return (unsigned short)(r >> 16);
}
__device__ __forceinline__ float bf2f(unsigned short h) {
  return u_as_f(((unsigned)h) << 16);
}

// async global->LDS, 16 B per lane; LDS dst is wave-uniform base + lane*16
__device__ __forceinline__ void glds16(const unsigned short* g, unsigned short* l) {
  __builtin_amdgcn_global_load_lds(
      (const __attribute__((address_space(1))) unsigned int*)g,
      (__attribute__((address_space(3))) unsigned int*)l, 16, 0, 0);
}

// monotone float->u32 key; pack (value, col) so u64 max = (max val, tie->smaller col)
__device__ __forceinline__ unsigned fkey(float f) {
  unsigned u = f_as_u(f);
  return (u & 0x80000000u) ? ~u : (u | 0x80000000u);
}
__device__ __forceinline__ float funkey(unsigned k) {
  unsigned u = (k & 0x80000000u) ? (k ^ 0x80000000u) : ~k;
  return u_as_f(u);
}
__device__ __forceinline__ unsigned long long packkc(float v, int col) {
  return ((unsigned long long)fkey(v) << 32) | (unsigned)(~(unsigned)col);
}
__device__ __forceinline__ int unpack_col(unsigned long long w) {
  return (int)(~(unsigned)(w & 0xFFFFFFFFull));
}
__device__ __forceinline__ float unpack_val(unsigned long long w) {
  return funkey((unsigned)(w >> 32));
}
__device__ __forceinline__ unsigned long long shfl_xor_u64(unsigned long long x, int m) {
  unsigned lo = (unsigned)x, hi = (unsigned)(x >> 32);
  lo = __shfl_xor(lo, m, 64);
  hi = __shfl_xor(hi, m, 64);
  return ((unsigned long long)hi << 32) | lo;
}

// ---------------- weight transposes ----------------
// generic: src K x N fp32 -> dst N x K bf16 (hi, optional lo)
__global__ void transpose_cast_kernel(const float* __restrict__ src,
                                      unsigned short* __restrict__ dhi,
                                      unsigned short* __restrict__ dlo,
                                      int K, int N) {
  __shared__ float tile[32][33];
  int n0 = blockIdx.x * 32, k0 = blockIdx.y * 32;
  int tx = threadIdx.x, ty = threadIdx.y;  // 32 x 8
  for (int r = ty; r < 32; r += 8)
    tile[r][tx] = src[(size_t)(k0 + r) * N + n0 + tx];
  __syncthreads();
  for (int r = ty; r < 32; r += 8) {
    float v = tile[tx][r];
    size_t o = (size_t)(n0 + r) * K + k0 + tx;
    unsigned short h = f2bf(v);
    dhi[o] = h;
    if (dlo) dlo[o] = f2bf(v - bf2f(h));
  }
}

// three 512x512 weights -> Wcat [1536,512] bf16 (slab order: z=0 Wk, 1 Wv, 2 Wq)
__global__ void transpose_cast3_kernel(const float* __restrict__ s0,
                                       const float* __restrict__ s1,
                                       const float* __restrict__ s2,
                                       unsigned short* __restrict__ dhi) {
  __shared__ float tile[32][33];
  const float* src = blockIdx.z == 0 ? s0 : (blockIdx.z == 1 ? s1 : s2);
  unsigned short* d = dhi + (size_t)blockIdx.z * 512 * 512;
  int n0 = blockIdx.x * 32, k0 = blockIdx.y * 32;
  int tx = threadIdx.x, ty = threadIdx.y;
  for (int r = ty; r < 32; r += 8)
    tile[r][tx] = src[(size_t)(k0 + r) * 512 + n0 + tx];
  __syncthreads();
  for (int r = ty; r < 32; r += 8)
    d[(size_t)(n0 + r) * 512 + k0 + tx] = f2bf(tile[tx][r]);
}

// ---------------- block reduce (256 threads = 4 waves) ----------------
__device__ __forceinline__ float block_sum_256(float v, float* sm4) {
#pragma unroll
  for (int off = 32; off; off >>= 1) v += __shfl_down(v, off, 64);
  __syncthreads();
  if ((threadIdx.x & 63) == 0) sm4[threadIdx.x >> 6] = v;
  __syncthreads();
  return (sm4[0] + sm4[1]) + (sm4[2] + sm4[3]);
}

// ---------------- layernorm kernels ----------------
__global__ __launch_bounds__(256) void ln_x_kernel(
    const float* __restrict__ in, const float* __restrict__ w,
    const float* __restrict__ b, unsigned short* __restrict__ out_hi) {
  __shared__ float sm4[4];
  int row = blockIdx.x, tid = threadIdx.x;
  const float* r = in + (size_t)row * 512;
  float x0 = r[tid], x1 = r[tid + 256];
  float mu = block_sum_256(x0 + x1, sm4) * (1.0f / 512.0f);
  float d0 = x0 - mu, d1 = x1 - mu;
  float var = block_sum_256(d0 * d0 + d1 * d1, sm4) * (1.0f / 512.0f);
  float rs = rsqrtf(var + 1e-5f);
  out_hi[(size_t)row * 512 + tid]       = f2bf(d0 * rs * w[tid] + b[tid]);
  out_hi[(size_t)row * 512 + tid + 256] = f2bf(d1 * rs * w[tid + 256] + b[tid + 256]);
}

__global__ __launch_bounds__(256) void ln_e_kernel(
    const float* __restrict__ noise, const float* __restrict__ mu_e,
    const float* __restrict__ ls_e, const float* __restrict__ w,
    const float* __restrict__ b, unsigned short* __restrict__ e1_hi,
    unsigned short* __restrict__ e1_lo) {
  __shared__ float sm4[4];
  int row = blockIdx.x, tid = threadIdx.x;
  const float* r = noise + (size_t)row * 512;
  float x0 = mu_e[tid] + expf(ls_e[tid]) * r[tid];
  float x1 = mu_e[tid + 256] + expf(ls_e[tid + 256]) * r[tid + 256];
  float mu = block_sum_256(x0 + x1, sm4) * (1.0f / 512.0f);
  float d0 = x0 - mu, d1 = x1 - mu;
  float var = block_sum_256(d0 * d0 + d1 * d1, sm4) * (1.0f / 512.0f);
  float rs = rsqrtf(var + 1e-5f);
  float y0 = d0 * rs * w[tid] + b[tid];
  float y1 = d1 * rs * w[tid + 256] + b[tid + 256];
  size_t o = (size_t)row * 1024;
  unsigned short h0 = f2bf(y0), h1 = f2bf(y1);
  e1_hi[o + tid] = h0;             e1_lo[o + tid] = f2bf(y0 - bf2f(h0));
  e1_hi[o + tid + 256] = h1;       e1_lo[o + tid + 256] = f2bf(y1 - bf2f(h1));
}

// ---------------- gemm128 core: 128x128 tile, K=512 fixed, glds staging ----
// A [M,512], B [N,512] row-major bf16, both row stride 512.
// acc layout: acc[i][t][r] -> C row bm + wave*32 + i*16 + quad*4 + r,
//                             col bn + t*16 + (lane&15)
#define GEMM128_CORE(A_, B_, bm_, bn_, acc_)                                   \
  __shared__ __align__(16) unsigned short As[128 * 32];                        \
  __shared__ __align__(16) unsigned short Bs[128 * 32];                        \
  {                                                                            \
    const unsigned short* gA0 = (A_) + ((bm_) + (tid >> 2)) * 512 + ((tid & 3) << 3); \
    const unsigned short* gA1 = gA0 + 64 * 512;                                \
    const unsigned short* gB0 = (B_) + ((bn_) + (tid >> 2)) * 512 + ((tid & 3) << 3); \
    const unsigned short* gB1 = gB0 + 64 * 512;                                \
    unsigned short* dA0 = &As[wave * 512];                                     \
    unsigned short* dA1 = &As[2048 + wave * 512];                              \
    unsigned short* dB0 = &Bs[wave * 512];                                     \
    unsigned short* dB1 = &Bs[2048 + wave * 512];                              \
    for (int k0 = 0; k0 < 512; k0 += 32) {                                     \
      glds16(gA0 + k0, dA0);                                                   \
      glds16(gA1 + k0, dA1);                                                   \
      glds16(gB0 + k0, dB0);                                                   \
      glds16(gB1 + k0, dB1);                                                   \
      __syncthreads();                                                         \
      bf16x8 af0 = *(const bf16x8*)&As[(wave * 32 + lrow) * 32 + quad * 8];    \
      bf16x8 af1 = *(const bf16x8*)&As[(wave * 32 + 16 + lrow) * 32 + quad * 8]; \
      _Pragma("unroll")                                                        \
      for (int t = 0; t < 8; ++t) {                                            \
        bf16x8 bfr = *(const bf16x8*)&Bs[(t * 16 + lrow) * 32 + quad * 8];     \
        acc_[0][t] = __builtin_amdgcn_mfma_f32_16x16x32_bf16(af0, bfr, acc_[0][t], 0, 0, 0); \
        acc_[1][t] = __builtin_amdgcn_mfma_f32_16x16x32_bf16(af1, bfr, acc_[1][t], 0, 0, 0); \
      }                                                                        \
      __syncthreads();                                                         \
    }                                                                          \
  }

// dots / dots2: C = alpha * A@B^T (fp32 out)
__global__ __launch_bounds__(256) void gemm128_dots_kernel(
    const unsigned short* __restrict__ A, const unsigned short* __restrict__ B,
    float alpha, float* __restrict__ C, int ldc) {
  int tid = threadIdx.x, wave = tid >> 6, lane = tid & 63;
  int lrow = lane & 15, quad = lane >> 4;
  size_t bm = (size_t)blockIdx.x * 128, bn = (size_t)blockIdx.y * 128;
  floatx4 zero4 = {0.f, 0.f, 0.f, 0.f};
  floatx4 acc[2][8];
#pragma unroll
  for (int i = 0; i < 2; ++i)
#pragma unroll
    for (int t = 0; t < 8; ++t) acc[i][t] = zero4;
  GEMM128_CORE(A, B, bm, bn, acc)
#pragma unroll
  for (int i = 0; i < 2; ++i) {
    size_t row0 = bm + wave * 32 + i * 16 + quad * 4;
#pragma unroll
    for (int t = 0; t < 8; ++t) {
      int col = (int)bn + t * 16 + lrow;
#pragma unroll
      for (int r = 0; r < 4; ++r)
        C[(row0 + r) * (size_t)ldc + col] = acc[i][t][r] * alpha;
    }
  }
}

// fused k/v/q2: A = x [16384,512]; B = Wcat [1536,512] (slabs: Wk, Wv, Wq).
// block col slab: bn>>9 -> 0:k (relu), 1:v (relu), 2:q2 (no relu). All ld 512.
__global__ __launch_bounds__(256) void gemm128_kvq_kernel(
    const unsigned short* __restrict__ A, const unsigned short* __restrict__ B,
    const float* __restrict__ bk, const float* __restrict__ bv,
    const float* __restrict__ bq,
    unsigned short* __restrict__ khi, unsigned short* __restrict__ vhi,
    unsigned short* __restrict__ q2hi) {
  int tid = threadIdx.x, wave = tid >> 6, lane = tid & 63;
  int lrow = lane & 15, quad = lane >> 4;
  size_t bm = (size_t)blockIdx.x * 128, bn = (size_t)blockIdx.y * 128;
  floatx4 zero4 = {0.f, 0.f, 0.f, 0.f};
  floatx4 acc[2][8];
#pragma unroll
  for (int i = 0; i < 2; ++i)
#pragma unroll
    for (int t = 0; t < 8; ++t) acc[i][t] = zero4;
  GEMM128_CORE(A, B, bm, bn, acc)
  int mat = (int)(bn >> 9);
  int colbase = (int)(bn & 511);
  const float* bias = mat == 0 ? bk : (mat == 1 ? bv : bq);
  unsigned short* dst = mat == 0 ? khi : (mat == 1 ? vhi : q2hi);
  bool relu = mat < 2;
#pragma unroll
  for (int i = 0; i < 2; ++i) {
    size_t row0 = bm + wave * 32 + i * 16 + quad * 4;
#pragma unroll
    for (int t = 0; t < 8; ++t) {
      int col = colbase + t * 16 + lrow;
      float bvv = bias[col];
#pragma unroll
      for (int r = 0; r < 4; ++r) {
        float v = acc[i][t][r] + bvv;
        if (relu) v = fmaxf(v, 0.0f);
        dst[(row0 + r) * 512 + col] = f2bf(v);
      }
    }
  }
}

// ---------------- GEMM, 64x64 tile, optional 3-term hi/lo split ----------------
template <bool SPLIT, bool RELU, bool HAS_BIAS, bool WF32, bool WHI, bool WLO>
__global__ __launch_bounds__(256) void gemm64_kernel(
    const unsigned short* __restrict__ Ahi, const unsigned short* __restrict__ Alo, int lda,
    const unsigned short* __restrict__ Bhi, const unsigned short* __restrict__ Blo, int K,
    const float* __restrict__ bias, float alpha,
    float* __restrict__ Cf, int ldc,
    unsigned short* __restrict__ Chi, unsigned short* __restrict__ Clo, int ldcb) {
  __shared__ __align__(16) unsigned short AsH[64 * 32];
  __shared__ __align__(16) unsigned short BsH[64 * 32];
  __shared__ __align__(16) unsigned short AsL[64 * 32];
  __shared__ __align__(16) unsigned short BsL[64 * 32];
  int tid = threadIdx.x, wave = tid >> 6, lane = tid & 63;
  int lrow = lane & 15, quad = lane >> 4;
  size_t bm = (size_t)blockIdx.x * 64, bn = (size_t)blockIdx.y * 64;
  int row = tid >> 2, off = (tid & 3) << 3;
  size_t aoff = (bm + row) * (size_t)lda + off;
  size_t boff = (bn + row) * (size_t)K + off;

  floatx4 zero4 = {0.f, 0.f, 0.f, 0.f};
  floatx4 acc[4];
#pragma unroll
  for (int t = 0; t < 4; ++t) acc[t] = zero4;

  for (int k0 = 0; k0 < K; k0 += 32) {
    uint4 ah = *(const uint4*)(Ahi + aoff + k0);
    uint4 bh = *(const uint4*)(Bhi + boff + k0);
    uint4 al, bl;
    if (SPLIT) {
      al = *(const uint4*)(Alo + aoff + k0);
      bl = *(const uint4*)(Blo + boff + k0);
    }
    __syncthreads();
    *(uint4*)&AsH[tid * 8] = ah;
    *(uint4*)&BsH[tid * 8] = bh;
    if (SPLIT) {
      *(uint4*)&AsL[tid * 8] = al;
      *(uint4*)&BsL[tid * 8] = bl;
    }
    __syncthreads();
    int ai = (wave * 16 + lrow) * 32 + quad * 8;
    bf16x8 aH = *(const bf16x8*)&AsH[ai];
    bf16x8 aL;
    if (SPLIT) aL = *(const bf16x8*)&AsL[ai];
#pragma unroll
    for (int t = 0; t < 4; ++t) {
      int bi = (t * 16 + lrow) * 32 + quad * 8;
      bf16x8 bH = *(const bf16x8*)&BsH[bi];
      acc[t] = __builtin_amdgcn_mfma_f32_16x16x32_bf16(aH, bH, acc[t], 0, 0, 0);
      if (SPLIT) {
        bf16x8 bL = *(const bf16x8*)&BsL[bi];
        acc[t] = __builtin_amdgcn_mfma_f32_16x16x32_bf16(aH, bL, acc[t], 0, 0, 0);
        acc[t] = __builtin_amdgcn_mfma_f32_16x16x32_bf16(aL, bH, acc[t], 0, 0, 0);
      }
    }
  }
  size_t row0 = bm + wave * 16 + quad * 4;
#pragma unroll
  for (int t = 0; t < 4; ++t) {
    int col = (int)bn + t * 16 + lrow;
    float bv = HAS_BIAS ? bias[col] : 0.0f;
#pragma unroll
    for (int r = 0; r < 4; ++r) {
      float v = acc[t][r] * alpha + bv;
      if (RELU) v = fmaxf(v, 0.0f);
      if (WF32) Cf[(row0 + r) * (size_t)ldc + col] = v;
      if (WHI) {
        unsigned short h = f2bf(v);
        Chi[(row0 + r) * (size_t)ldcb + col] = h;
        if (WLO) Clo[(row0 + r) * (size_t)ldcb + col] = f2bf(v - bf2f(h));
      }
    }
  }
}

// ---------------- top-4 register insertion ----------------
#define INSERT4(lv, li, v, col)                                   \
  do {                                                            \
    if ((v) > lv[3]) {                                            \
      float cv_ = (v); int ci_ = (col);                           \
      _Pragma("unroll")                                           \
      for (int j_ = 0; j_ < 4; ++j_) {                            \
        bool sw_ = (cv_ > lv[j_]);                                \
        float tv_ = sw_ ? lv[j_] : cv_;                           \
        int ti_ = sw_ ? li[j_] : ci_;                              \
        lv[j_] = sw_ ? cv_ : lv[j_];                              \
        li[j_] = sw_ ? ci_ : li[j_];                              \
        cv_ = tv_; ci_ = ti_;                                     \
      }                                                           \
    }                                                             \
  } while (0)

// ---------------- attention 1: 1 block (4 waves) per row of 16384 ----------
__global__ __launch_bounds__(256) void attn1_kernel(
    const float* __restrict__ dots,          // NE x NN
    const unsigned short* __restrict__ vhi,  // NN x 512 bf16
    unsigned short* __restrict__ e1_hi, unsigned short* __restrict__ e1_lo) {
  __shared__ float sm_m[4], sm_s[4];
  __shared__ unsigned long long wbest[4];
  __shared__ unsigned long long wkey_s[TOPK];

  int tid = threadIdx.x, wave = tid >> 6, lane = tid & 63;
  int rowi = blockIdx.x;
  const float4* r4 = (const float4*)(dots + (size_t)rowi * NN);

  float lv[4]; int li[4];
#pragma unroll
  for (int j = 0; j < 4; ++j) { lv[j] = -INFINITY; li[j] = 0x7fffffff; }
  unsigned long long selmask = 0ull;
  int taken = 0;

  float m_loc = -INFINITY, s_loc = 0.0f;
  for (int i = 0; i < 16; ++i) {
    float4 q = r4[tid + (i << 8)];
#pragma unroll
    for (int c = 0; c < 4; ++c) {
      float v = (&q.x)[c];
      int col = ((tid + (i << 8)) << 2) + c;
      if (v > m_loc) {
        s_loc = s_loc * __expf(m_loc - v) + 1.0f;
        m_loc = v;
      } else {
        s_loc += __expf(v - m_loc);
      }
      INSERT4(lv, li, v, col);
    }
  }
#pragma unroll
  for (int sft = 32; sft; sft >>= 1) {
    float om = __shfl_xor(m_loc, sft, 64);
    float os = __shfl_xor(s_loc, sft, 64);
    float M = fmaxf(m_loc, om);
    s_loc = s_loc * __expf(m_loc - M) + os * __expf(om - M);
    m_loc = M;
  }
  if (lane == 0) { sm_m[wave] = m_loc; sm_s[wave] = s_loc; }
  __syncthreads();
  float M = fmaxf(fmaxf(sm_m[0], sm_m[1]), fmaxf(sm_m[2], sm_m[3]));
  float Z = sm_s[0] * __expf(sm_m[0] - M) + sm_s[1] * __expf(sm_m[1] - M) +
            sm_s[2] * __expf(sm_m[2] - M) + sm_s[3] * __expf(sm_m[3] - M);

  for (int rnd = 0; rnd < TOPK; ++rnd) {
    unsigned long long key;
    if (taken < 4) {
      key = packkc(lv[0], li[0]);
    } else {  // rare: rescan this thread's 64 values from L2, excluding taken
      key = 0ull;
      for (int i = 0; i < 16; ++i) {
        float4 q = r4[tid + (i << 8)];
#pragma unroll
        for (int c = 0; c < 4; ++c) {
          int sl = i * 4 + c;
          if (!((selmask >> sl) & 1ull)) {
            int col = ((tid + (i << 8)) << 2) + c;
            unsigned long long kk = packkc((&q.x)[c], col);
            if (kk > key) key = kk;
          }
        }
      }
    }
#pragma unroll
    for (int sft = 32; sft; sft >>= 1) {
      unsigned long long ok = shfl_xor_u64(key, sft);
      if (ok > key) key = ok;
    }
    if (lane == 0) wbest[wave] = key;
    __syncthreads();
    unsigned long long w = wbest[0];
    if (wbest[1] > w) w = wbest[1];
    if (wbest[2] > w) w = wbest[2];
    if (wbest[3] > w) w = wbest[3];
    if (tid == 0) wkey_s[rnd] = w;
    int wcol = unpack_col(w);
    if (((wcol >> 2) & 255) == tid) {
      int sl = ((wcol >> 10) << 2) | (wcol & 3);
      selmask |= (1ull << sl);
      if (taken < 4) {
#pragma unroll
        for (int j = 0; j < 3; ++j) { lv[j] = lv[j + 1]; li[j] = li[j + 1]; }
      }
      ++taken;
    }
    __syncthreads();
  }

  const float inv_den = 1.0f / (1.0f + (float)NN * EPS_F);
  float invZ = 1.0f / Z;
  float u0 = 0.f, u1 = 0.f;
#pragma unroll
  for (int j = 0; j < TOPK; ++j) {
    unsigned long long w = wkey_s[j];
    int col = unpack_col(w);
    float val = unpack_val(w);
    float a = (__expf(val - M) * invZ + EPS_F) * inv_den;
    const unsigned short* vr = vhi + (size_t)col * 512;
    u0 += a * bf2f(vr[tid]);
    u1 += a * bf2f(vr[tid + 256]);
  }
  size_t o = (size_t)rowi * 1024 + 512;
  unsigned short h0 = f2bf(u0), h1 = f2bf(u1);
  e1_hi[o + tid] = h0;             e1_lo[o + tid] = f2bf(u0 - bf2f(h0));
  e1_hi[o + tid + 256] = h1;       e1_lo[o + tid + 256] = f2bf(u1 - bf2f(h1));
}

// ---------------- attention 2: 1 wave per row of 2048 (4 rows/block) -------
__global__ __launch_bounds__(256) void attn2_kernel(const float* __restrict__ dots2,
                                                    float* __restrict__ Hout) {
  int tid = threadIdx.x, wave = tid >> 6, lane = tid & 63;
  int rowi = blockIdx.x * 4 + wave;
  const float4* r4 = (const float4*)(dots2 + (size_t)rowi * NE);

  float d[32];
  float m = -INFINITY;
#pragma unroll
  for (int i = 0; i < 8; ++i) {
    float4 q = r4[lane + (i << 6)];
#pragma unroll
    for (int c = 0; c < 4; ++c) {
      d[i * 4 + c] = (&q.x)[c];
      m = fmaxf(m, d[i * 4 + c]);
    }
  }
#pragma unroll
  for (int sft = 32; sft; sft >>= 1) m = fmaxf(m, __shfl_xor(m, sft, 64));

  float s = 0.f;
#pragma unroll
  for (int j = 0; j < 32; ++j) { d[j] = __expf(d[j] - m); s += d[j]; }
#pragma unroll
  for (int sft = 32; sft; sft >>= 1) s += __shfl_xor(s, sft, 64);
  float invZ = 1.0f / s;

  float lv[4]; int li[4];
#pragma unroll
  for (int j = 0; j < 4; ++j) { lv[j] = -INFINITY; li[j] = 0x7fffffff; }
#pragma unroll
  for (int i = 0; i < 8; ++i) {
#pragma unroll
    for (int c = 0; c < 4; ++c) {
      int col = ((lane + (i << 6)) << 2) + c;
      INSERT4(lv, li, d[i * 4 + c], col);
    }
  }

  unsigned selmask = 0;
  int taken = 0;
  for (int rnd = 0; rnd < TOPK; ++rnd) {
    unsigned long long key;
    if (taken < 4) {
      key = packkc(lv[0], li[0]);
    } else {
      key = 0ull;
#pragma unroll
      for (int j = 0; j < 32; ++j) {
        if (!((selmask >> j) & 1u)) {
          int col = ((lane + ((j >> 2) << 6)) << 2) + (j & 3);
          unsigned long long kk = packkc(d[j], col);
          if (kk > key) key = kk;
        }
      }
    }
#pragma unroll
    for (int sft = 32; sft; sft >>= 1) {
      unsigned long long ok = shfl_xor_u64(key, sft);
      if (ok > key) key = ok;
    }
    int wcol = unpack_col(key);
    if (((wcol >> 2) & 63) == lane) {
      int sl = ((wcol >> 8) << 2) | (wcol & 3);
      selmask |= (1u << sl);
      if (taken < 4) {
#pragma unroll
        for (int j = 0; j < 3; ++j) { lv[j] = lv[j + 1]; li[j] = li[j + 1]; }
      }
      ++taken;
    }
  }

  float* hr = Hout + (size_t)rowi * NE;
#pragma unroll
  for (int i = 0; i < 8; ++i) {
    float4 o;
#pragma unroll
    for (int c = 0; c < 4; ++c) {
      int sl = i * 4 + c;
      (&o.x)[c] = ((selmask >> sl) & 1u) ? d[sl] * invZ : 0.0f;
    }
    ((float4*)hr)[lane + (i << 6)] = o;
  }
}

// ---------------------------------------------------------------------------
extern "C" void kernel_launch(void* const* d_in, const int* in_sizes, int n_in,
                              void* d_out, int out_size, void* d_ws, size_t ws_size,
                              hipStream_t stream) {
  (void)in_sizes; (void)n_in; (void)out_size; (void)ws_size;
  const float* inputs  = (const float*)d_in[0];
  const float* noise   = (const float*)d_in[1];
  const float* edges_mu = (const float*)d_in[2];
  const float* edges_ls = (const float*)d_in[3];
  const float* Wq = (const float*)d_in[4];
  const float* bq = (const float*)d_in[5];
  const float* Wk = (const float*)d_in[6];
  const float* bk = (const float*)d_in[7];
  const float* Wv = (const float*)d_in[8];
  const float* bv = (const float*)d_in[9];
  const float* W1 = (const float*)d_in[10];
  const float* b1 = (const float*)d_in[11];
  const float* W2 = (const float*)d_in[12];
  const float* b2 = (const float*)d_in[13];
  const float* ln_in_w = (const float*)d_in[14];
  const float* ln_in_b = (const float*)d_in[15];
  const float* ln_e_w = (const float*)d_in[16];
  const float* ln_e_b = (const float*)d_in[17];

  float* out_e  = (float*)d_out;                  // [2048,512]
  float* out_H  = out_e + (size_t)NE * 512;       // [16384,2048]
  float* out_d2 = out_H + (size_t)NN * NE;        // [16384,2048]

  const size_t MB = 1024 * 1024;
  // Scratch now in the H output region (dead before attn2 writes H).
  unsigned char* hb = (unsigned char*)out_H;
  unsigned short* x_hi  = (unsigned short*)(hb);                 // 16 MB
  unsigned short* k_hi  = (unsigned short*)(hb + 16 * MB);       // 16 MB
  unsigned short* v_hi  = (unsigned short*)(hb + 32 * MB);       // 16 MB
  unsigned short* q2_hi = (unsigned short*)(hb + 48 * MB);       // 16 MB
  unsigned short* WcatT = (unsigned short*)(hb + 64 * MB);       // 1.5 MB [Wk;Wv;Wq]^T
  unsigned short* W1Th  = (unsigned short*)(hb + 66 * MB);       // 1 MB
  unsigned short* W1Tl  = (unsigned short*)(hb + 67 * MB);       // 1 MB
  unsigned short* W2Th  = (unsigned short*)(hb + 68 * MB);       // 0.5 MB
  unsigned short* W2Tl  = (unsigned short*)(hb + 68 * MB + 512 * 1024);
  unsigned short* e1_hi = (unsigned short*)(hb + 70 * MB);       // 4 MB [2048,1024]
  unsigned short* e1_lo = (unsigned short*)(hb + 74 * MB);       // 4 MB
  unsigned short* q_hi  = (unsigned short*)(hb + 78 * MB);       // 2 MB
  unsigned short* h_hi  = (unsigned short*)(hb + 80 * MB);       // 2 MB
  unsigned short* h_lo  = (unsigned short*)(hb + 82 * MB);       // 2 MB
  unsigned short* e_hi  = (unsigned short*)(hb + 84 * MB);       // 2 MB
  unsigned short* WkT   = WcatT;                                 // slab 0
  unsigned short* WqT   = WcatT + (size_t)1024 * 512;            // slab 2
  // dots fp32 scratch lives in the dots2 output region (consumed by attn1
  // before the dots2 GEMM overwrites the region).
  float* dots = out_d2;
  unsigned short* k2_hi = (unsigned short*)d_ws;                 // 2 MB true ws

  dim3 tb(256);
  dim3 t32(32, 8);

  // weights -> transposed bf16
  transpose_cast3_kernel<<<dim3(16, 16, 3), t32, 0, stream>>>(Wk, Wv, Wq, WcatT);
  transpose_cast_kernel<<<dim3(16, 32), t32, 0, stream>>>(W1, W1Th, W1Tl, 1024, 512);
  transpose_cast_kernel<<<dim3(16, 16), t32, 0, stream>>>(W2, W2Th, W2Tl, 512, 512);

  ln_x_kernel<<<NN, tb, 0, stream>>>(inputs, ln_in_w, ln_in_b, x_hi);
  ln_e_kernel<<<NE, tb, 0, stream>>>(noise, edges_mu, edges_ls, ln_e_w, ln_e_b, e1_hi, e1_lo);

  // k = relu(x@Wk+bk), v = relu(x@Wv+bv), q2 = x@Wq+bq  (one fused GEMM)
  gemm128_kvq_kernel<<<dim3(128, 12), tb, 0, stream>>>(
      x_hi, WcatT, bk, bv, bq, k_hi, v_hi, q2_hi);
  // q = relu(e0@Wq+bq)
  gemm64_kernel<false, true, true, false, true, false><<<dim3(32, 8), tb, 0, stream>>>(
      e1_hi, nullptr, 1024, WqT, nullptr, 512, bq, 1.f, nullptr, 0, q_hi, nullptr, 512);
  // dots = q@k^T * SCALE -> dots2-region scratch
  gemm128_dots_kernel<<<dim3(16, 128), tb, 0, stream>>>(q_hi, k_hi, SCALE_F, dots, NN);
  // attn1 -> updates into e1[:,512:]
  attn1_kernel<<<NE, tb, 0, stream>>>(dots, v_hi, e1_hi, e1_lo);
  // h = relu(e1@W1+b1)  (SPLIT)
  gemm64_kernel<true, true, true, false, true, true><<<dim3(32, 8), tb, 0, stream>>>(
      e1_hi, e1_lo, 1024, W1Th, W1Tl, 1024, b1, 1.f, nullptr, 0, h_hi, h_lo, 512);
  // e = h@W2+b2  (SPLIT) -> OUTPUT 0 + bf16 hi
  gemm64_kernel<true, false, true, true, true, false><<<dim3(32, 8), tb, 0, stream>>>(
      h_hi, h_lo, 512, W2Th, W2Tl, 512, b2, 1.f, out_e, 512, e_hi, nullptr, 512);
  // k2 = relu(e@Wk+bk)
  gemm64_kernel<false, true, true, false, true, false><<<dim3(32, 8), tb, 0, stream>>>(
      e_hi, nullptr, 512, WkT, nullptr, 512, bk, 1.f, nullptr, 0, k2_hi, nullptr, 512);
  // dots2 = q2@k2^T * SCALE -> OUTPUT 2 (overwrites dots scratch, already consumed)
  gemm128_dots_kernel<<<dim3(128, 16), tb, 0, stream>>>(q2_hi, k2_hi, SCALE_F, out_d2, NE);
  // attn2 -> OUTPUT 1 (H), overwrites all H-region scratch (dead)
  attn2_kernel<<<NN / 4, tb, 0, stream>>>(out_d2, out_H);
}